// Round 15
// baseline (199.462 us; speedup 1.0000x reference)
//
#include <hip/hip_runtime.h>
#include <hip/hip_bf16.h>
#include <cstddef>
#include <cstdint>

// (B,T,I,H,K) = (32,1024,512,512,2)
#define B_  32
#define T_  1024
#define I_  512
#define H_  512
#define M_  (B_ * T_)     // 32768

typedef __bf16 bf16x8  __attribute__((ext_vector_type(8)));
typedef float  floatx4 __attribute__((ext_vector_type(4)));
typedef unsigned short ushort8v __attribute__((ext_vector_type(8)));
typedef unsigned long long u64;

__device__ __forceinline__ unsigned short f2bf(float f) {
    return __builtin_bit_cast(unsigned short, (__bf16)f);
}
__device__ __forceinline__ float sigm(float x) {
    return __builtin_amdgcn_rcpf(1.f + __expf(-x));
}

// ---------------------------------------------------------------------------
// Prep, SHRUNK (round-13 post-mortem: part 1 (Ab2 build, 8200 blocks) was
// pure BW cost ~20-30us; its work is now fused into the gemm's A-staging.
// Remaining: part 2 weight pack (512 blocks) + part 3 zero Hpub/tickets.
//  Wq[gate(2)][ni(4)][ksub(32)][wn(2)][c(4)][lane(64)][8] bf16.
//  Hpub pos-7 slice (last 128 KB) doubles as the gemm's zero-pad source for
//  the t=-1 row: it is zeroed here and never written by the gemm.
// ---------------------------------------------------------------------------
#define NB_PACK  512     // 1,048,576 elems / 8 / 256
#define NB_ZERO  256     // 1 MB / 16 B / 256

__global__ __launch_bounds__(256) void prep(const float* __restrict__ Wf,
                                            const float* __restrict__ Wz,
                                            unsigned short* __restrict__ Wq,
                                            uint4* __restrict__ HpubZ,
                                            uint32_t* __restrict__ tickets) {
    if (blockIdx.x < NB_PACK) {
        int cid = blockIdx.x * 256 + threadIdx.x;  // 0..131071
        int lane = cid & 63;
        int c    = (cid >> 6) & 3;
        int wn   = (cid >> 8) & 1;
        int ksub = (cid >> 9) & 31;
        int ni   = (cid >> 14) & 3;
        int gate = (cid >> 16) & 1;
        int n_col = ni * 128 + wn * 64 + c * 16 + (lane & 15);
        const float* G = gate ? Wz : Wf;
        ushort8v o;
        #pragma unroll
        for (int j = 0; j < 8; ++j) {
            int k   = ksub * 32 + (lane >> 4) * 8 + j;
            int tap = k >> 9;
            int i   = k & 511;
            o[j] = f2bf(G[n_col * (I_ * 2) + i * 2 + tap]);
        }
        *(ushort8v*)&Wq[(size_t)cid * 8] = o;
    } else {
        int g = (blockIdx.x - NB_PACK) * 256 + threadIdx.x;  // 0..65535
        HpubZ[g] = make_uint4(0, 0, 0, 0);
        if (g < 128) tickets[g] = 0;
    }
}

// ---------------------------------------------------------------------------
// Fused dual-gate MFMA GEMM + full scan via decoupled lookback.
//
// R13 post-mortem: native-cvt prep changed nothing (non-gemm constant
// 105us across R12/R13) => prep part 1 is BW-bound ~20-30us; rest of the
// 105 is fixed overhead. This round DELETES part 1 by fusing the fp32->bf16
// conversion into the gemm's A staging:
//   A staged from x as fp32 via registers (4 coalesced float4/wave/step,
//   issued one step ahead), converted with native bf16 cast (RTNE, bit-
//   identical to prep's conversion), ds_write_b128 into the SAME bf16 LDS
//   layout as R13 -> RDA/MFMA/LOADB/epilogue byte-identical, absmax
//   unchanged. Ring-2 slots (8 KB each). Per step:
//     s_waitcnt vmcnt(0) lgkmcnt(0); s_barrier;    // all 1-step-covered
//     LOADB(k+1); CVT+ds_write A(k+1)->slot[(k+1)&1]; LOADA(k+2);
//     sched_barrier; RDA slot[k&1]; MFMA with B(k).
//   t=-1 zero row: per-lane redirect (pos==0 && row==0 && tap==0; 4 lanes)
//   to Hpub's zeroed, never-written pos-7 slice.
// Decode/tickets (4 ni-sharers same-XCD, per-chain pos ranks) = R13.
// ---------------------------------------------------------------------------
__global__ __launch_bounds__(256, 2) void mfma_gemm_scan(
        const float* __restrict__ x,             // [32][1024][512] fp32
        const unsigned short* __restrict__ Wq,   // fragment-ordered, 2 MB
        const float* __restrict__ biasF,
        const float* __restrict__ biasZ,
        float* __restrict__ out,                 // [M_][512] fp32
        u64* __restrict__ Hpub,                  // [8][128][128]
        uint32_t* __restrict__ tickets) {        // 128 chain counters
    // A ring: 2 slots of 4096 shorts (8 KB each), 16 KB total.
    // Epilogue reuse: seg = float2[32][128] at [0,32KB); hinL at [32KB,48KB)
    __shared__ unsigned short smem[24576];       // 48 KB
    __shared__ uint32_t pos_s;

    const int tid = threadIdx.x;
    const int bid = blockIdx.x;
    const int xcd = bid & 7;
    const int ni  = (bid >> 3) & 3;
    const int q   = bid >> 5;                    // 0..31
    const int b   = ((q & 3) << 3) | xcd;        // 0..31
    const int chain = ni * 32 + b;               // 0..127
    if (tid == 0) pos_s = atomicAdd(&tickets[chain], 1u);
    __syncthreads();
    const int pos = (int)pos_s;                  // 0..7 = start rank in chain
    const int h0  = ni * 128;
    const int trow0 = pos * 128;                 // tile's first t-row

    const int lane = tid & 63;
    const int wave = tid >> 6;
    const int wm   = wave >> 1, wn = wave & 1;
    const int lm   = lane & 15, quad = lane >> 4;

    // A staging chunk ids (512 bf16-chunks/slot; wave covers c0, c1=c0+64)
    const int c0 = wave * 128 + lane;
    const int c1 = c0 + 64;
    const int r0 = c0 >> 2, q0 = (c0 & 3) ^ ((r0 >> 2) & 3);
    const int r1 = c1 >> 2, q1 = (c1 & 3) ^ ((r1 >> 2) & 3);

    // fp32 sources. tap0 row = x[b][trow0 + r - 1]; tap1 row = +1.
    // Zero row only when pos==0 && r0==0 (tap0): redirect to Hpub pos-7
    // slice (128 KB of zeros, never written by any block). r1 >= 16 always.
    const float* zp = (const float*)(Hpub + (size_t)7 * 128 * 128);
    const float* pt0_r0 = (pos == 0 && r0 == 0)
        ? (zp + q0 * 8)
        : (x + (size_t)(b * T_ + trow0 + r0 - 1) * 512 + q0 * 8);
    const float* pt1_r0 = x + (size_t)(b * T_ + trow0 + r0) * 512 + q0 * 8;
    const float* pt0_r1 = x + (size_t)(b * T_ + trow0 + r1 - 1) * 512 + q1 * 8;
    const float* pt1_r1 = x + (size_t)(b * T_ + trow0 + r1) * 512 + q1 * 8;

    // B direct global->VGPR (L2-hot), unchanged from R13.
    const unsigned short* pBF = Wq + ni * 131072 + wn * 2048 + lane * 8;

    int offA[4];
    #pragma unroll
    for (int r = 0; r < 4; ++r) {
        int ml = wm * 64 + r * 16 + lm;
        offA[r] = (4 * ml + (quad ^ ((ml >> 2) & 3))) * 8;
    }

    floatx4 accF[4][4] = {};
    floatx4 accZ[4][4] = {};
    bf16x8 bfA[4], bzA[4], bfB[4], bzB[4];
    float4 av0, av1, av2, av3;                   // A fp32 in flight

#define LOADA(ksub) do {                                                \
        const float* b0_ = ((ksub) & 16) ? pt1_r0 : pt0_r0;             \
        const float* b1_ = ((ksub) & 16) ? pt1_r1 : pt0_r1;             \
        const int io_ = ((ksub) & 15) * 32;                             \
        av0 = *(const float4*)(b0_ + io_);                              \
        av1 = *(const float4*)(b0_ + io_ + 4);                          \
        av2 = *(const float4*)(b1_ + io_);                              \
        av3 = *(const float4*)(b1_ + io_ + 4);                          \
    } while (0)

#define CVTW(slot) do {                                                 \
        bf16x8 w0_, w1_;                                                \
        _Pragma("unroll")                                               \
        for (int j = 0; j < 4; ++j) {                                   \
            w0_[j]     = (__bf16)av0[j];                                \
            w0_[4 + j] = (__bf16)av1[j];                                \
            w1_[j]     = (__bf16)av2[j];                                \
            w1_[4 + j] = (__bf16)av3[j];                                \
        }                                                               \
        *(bf16x8*)((slot) + c0 * 8) = w0_;                              \
        *(bf16x8*)((slot) + c1 * 8) = w1_;                              \
    } while (0)

#define LOADB(ksub, BF, BZ) do {                                        \
        const unsigned short* pf_ = pBF + (ksub) * 4096;                \
        _Pragma("unroll")                                               \
        for (int c = 0; c < 4; ++c) {                                   \
            BF[c] = *(const bf16x8*)(pf_ + c * 512);                    \
            BZ[c] = *(const bf16x8*)(pf_ + 524288 + c * 512);           \
        }                                                               \
    } while (0)

#define MFMA32(AF, BF, BZ) do {                                         \
        __builtin_amdgcn_s_setprio(1);                                  \
        _Pragma("unroll")                                               \
        for (int r = 0; r < 4; ++r) {                                   \
            _Pragma("unroll")                                           \
            for (int c = 0; c < 4; ++c) {                               \
                accF[r][c] = __builtin_amdgcn_mfma_f32_16x16x32_bf16(   \
                                AF[r], BF[c], accF[r][c], 0, 0, 0);     \
                accZ[r][c] = __builtin_amdgcn_mfma_f32_16x16x32_bf16(   \
                                AF[r], BZ[c], accZ[r][c], 0, 0, 0);     \
            }                                                           \
        }                                                               \
        __builtin_amdgcn_s_setprio(0);                                  \
    } while (0)

#define RDA(slot, AF) do {                                              \
        _Pragma("unroll")                                               \
        for (int r = 0; r < 4; ++r)                                     \
            AF[r] = *(const bf16x8*)((slot) + offA[r]);                 \
    } while (0)

#define WAITBAR() do {                                                  \
        asm volatile("s_waitcnt vmcnt(0) lgkmcnt(0)");                  \
        __builtin_amdgcn_s_barrier();                                   \
        asm volatile("" ::: "memory");                                  \
    } while (0)

    unsigned short* sl0 = smem;           // slot parity 0
    unsigned short* sl1 = smem + 4096;    // slot parity 1

    // prologue: A(0) -> slot0; A(1), B(0) in flight
    LOADA(0);
    asm volatile("s_waitcnt vmcnt(0)");
    CVTW(sl0);
    LOADA(1);
    LOADB(0, bfA, bzA);

    // steps 0..27 as pairs
    for (int p = 0; p < 14; ++p) {
        const int k = 2 * p;
        {   // even step k: read sl0, write sl1 with A(k+1)
            WAITBAR();
            LOADB(k + 1, bfB, bzB);
            CVTW(sl1);
            LOADA(k + 2);
            __builtin_amdgcn_sched_barrier(0);
            bf16x8 af_[4];
            RDA(sl0, af_);
            MFMA32(af_, bfA, bzA);
        }
        {   // odd step k+1: read sl1, write sl0 with A(k+2)
            WAITBAR();
            LOADB(k + 2, bfA, bzA);
            CVTW(sl0);
            LOADA(k + 3);
            __builtin_amdgcn_sched_barrier(0);
            bf16x8 af_[4];
            RDA(sl1, af_);
            MFMA32(af_, bfB, bzB);
        }
    }
    // step 28 (even)
    {
        WAITBAR();
        LOADB(29, bfB, bzB);
        CVTW(sl1);
        LOADA(30);
        __builtin_amdgcn_sched_barrier(0);
        bf16x8 af_[4];
        RDA(sl0, af_);
        MFMA32(af_, bfA, bzA);
    }
    // step 29 (odd)
    {
        WAITBAR();
        LOADB(30, bfA, bzA);
        CVTW(sl0);
        LOADA(31);
        __builtin_amdgcn_sched_barrier(0);
        bf16x8 af_[4];
        RDA(sl1, af_);
        MFMA32(af_, bfB, bzB);
    }
    // step 30 (even): last write (A(31)->sl1), no more A loads
    {
        WAITBAR();
        LOADB(31, bfB, bzB);
        CVTW(sl1);
        __builtin_amdgcn_sched_barrier(0);
        bf16x8 af_[4];
        RDA(sl0, af_);
        MFMA32(af_, bfA, bzA);
    }
    // step 31 (odd): drain, read sl1
    {
        WAITBAR();
        __builtin_amdgcn_sched_barrier(0);
        bf16x8 af_[4];
        RDA(sl1, af_);
        MFMA32(af_, bfB, bzB);
    }
#undef LOADA
#undef CVTW
#undef LOADB
#undef MFMA32
#undef RDA
#undef WAITBAR
    __syncthreads();   // all waves done with ring before smem is repurposed

    // ================= epilogue: sigmoid + segment affines =================
    float bfv[4], bzv[4];
    #pragma unroll
    for (int c = 0; c < 4; ++c) {
        int hc = h0 + wn * 64 + c * 16 + lm;
        bfv[c] = biasF[hc];
        bzv[c] = biasZ[hc];
    }

    float2* seg  = (float2*)smem;                // [32][128] 32 KB
    float*  hinL = (float*)&smem[16384];         // [32][128] 16 KB

    #pragma unroll
    for (int r = 0; r < 4; ++r) {
        const int sid = wm * 16 + r * 4 + quad;  // segment of 4 t's
        #pragma unroll
        for (int c = 0; c < 4; ++c) {
            float A = 1.f, C = 0.f;
            #pragma unroll
            for (int v = 0; v < 4; ++v) {
                float f = sigm(accF[r][c][v] + bfv[c]);
                float z = sigm(accZ[r][c][v] + bzv[c]);
                accF[r][c][v] = f;               // keep f
                accZ[r][c][v] = z;               // keep z
                A *= f;
                C = fmaf(f, C - z, z);
            }
            seg[sid * 128 + wn * 64 + c * 16 + lm] = make_float2(A, C);
        }
    }
    __syncthreads();

    // per-h block affine (threads 0..127), lookback, publish, local states
    if (tid < 128) {
        float At = 1.f, Ct = 0.f;
        #pragma unroll 8
        for (int s = 0; s < 32; ++s) {
            float2 sc = seg[s * 128 + tid];
            Ct = fmaf(sc.x, Ct, sc.y);
            At *= sc.x;
        }
        float Hin = 0.f;
        if (pos > 0) {
            u64* p = &Hpub[((size_t)(pos - 1) * 128 + chain) * 128 + tid];
            u64 v;
            while (((v = atomicAdd(p, 0ull)) >> 32) == 0ull)
                __builtin_amdgcn_s_sleep(2);
            Hin = __uint_as_float((uint32_t)v);
        }
        if (pos < 7) {
            float Hout = fmaf(At, Hin, Ct);
            u64 pv = 0x100000000ull | (u64)__float_as_uint(Hout);
            atomicExch(&Hpub[((size_t)pos * 128 + chain) * 128 + tid], pv);
        }
        // per-segment entry states
        float run = Hin;
        #pragma unroll 8
        for (int s = 0; s < 32; ++s) {
            hinL[s * 128 + tid] = run;
            float2 sc = seg[s * 128 + tid];
            run = fmaf(sc.x, run, sc.y);
        }
    }
    __syncthreads();

    // replay tile from registers, write output
    const int rowBase = b * T_ + pos * 128;
    #pragma unroll
    for (int r = 0; r < 4; ++r) {
        const int sid = wm * 16 + r * 4 + quad;
        #pragma unroll
        for (int c = 0; c < 4; ++c) {
            const int hc = h0 + wn * 64 + c * 16 + lm;
            float hs = hinL[sid * 128 + (hc - h0)];
            #pragma unroll
            for (int v = 0; v < 4; ++v) {
                float f = accF[r][c][v];
                float z = accZ[r][c][v];
                hs = fmaf(f, hs - z, z);
                const size_t row = (size_t)(rowBase + wm * 64 + r * 16 + quad * 4 + v);
                out[row * H_ + hc] = hs;
            }
        }
    }
}

// ---------------------------------------------------------------------------
extern "C" void kernel_launch(void* const* d_in, const int* in_sizes, int n_in,
                              void* d_out, int out_size, void* d_ws, size_t ws_size,
                              hipStream_t stream) {
    const float* x  = (const float*)d_in[0];
    const float* Wz = (const float*)d_in[2];
    const float* bz = (const float*)d_in[3];
    const float* Wf = (const float*)d_in[4];
    const float* bf = (const float*)d_in[5];
    float* out = (float*)d_out;

    char* ws = (char*)d_ws;
    unsigned short* Wq   = (unsigned short*)(ws);                           // 2 MB
    u64*            Hpub = (u64*)(ws + (size_t)2 * 1024 * 1024);            // 1 MB
    uint32_t*       tkt  = (uint32_t*)(ws + (size_t)3 * 1024 * 1024);       // 512 B

    prep<<<NB_PACK + NB_ZERO, 256, 0, stream>>>(Wf, Wz, Wq, (uint4*)Hpub, tkt);

    mfma_gemm_scan<<<1024, 256, 0, stream>>>(x, Wq, bf, bz, out, Hpub, tkt);
}